// Round 6
// baseline (230.972 us; speedup 1.0000x reference)
//
#include <hip/hip_runtime.h>
#include <hip/hip_bf16.h>

// B=4, N=256, H=128, E=32. M = B*N*N = 262144 rows, out[m][128] f32.

typedef __attribute__((ext_vector_type(8))) short bf16x8;
typedef __attribute__((ext_vector_type(4))) short bf16x4;
typedef __attribute__((ext_vector_type(4))) float f32x4;

__device__ __forceinline__ unsigned short f2bf(float f) {
  union { float f; unsigned u; } v; v.f = f;
  unsigned r = v.u + 0x7FFFu + ((v.u >> 16) & 1u);  // RNE
  return (unsigned short)(r >> 16);
}

__device__ __forceinline__ bf16x8 cvt8(float4 a, float4 b) {
  bf16x8 r;
  r[0] = (short)f2bf(a.x); r[1] = (short)f2bf(a.y);
  r[2] = (short)f2bf(a.z); r[3] = (short)f2bf(a.w);
  r[4] = (short)f2bf(b.x); r[5] = (short)f2bf(b.y);
  r[6] = (short)f2bf(b.z); r[7] = (short)f2bf(b.w);
  return r;
}

// ---------------- prep: S = node@W1s + b1 ; DT[b][k][j] = (node@W1d)^T ; bf16 transposed weights ----
__global__ void prep_kernel(const float* __restrict__ node, const float* __restrict__ W1,
                            const float* __restrict__ b1, const float* __restrict__ W2,
                            float* __restrict__ S, float* __restrict__ DT,
                            unsigned short* __restrict__ W1hT, unsigned short* __restrict__ W1eT,
                            unsigned short* __restrict__ W2T) {
  const int t = threadIdx.x;
  if (blockIdx.x < 256) {
    __shared__ float nrow[4 * 128];
    const int bi0 = blockIdx.x * 4;
    if (t < 128)
      reinterpret_cast<float4*>(nrow)[t] = reinterpret_cast<const float4*>(node + bi0 * 128)[t];
    __syncthreads();
    const int kc = t & 127, half = t >> 7;  // rows half*2, half*2+1
    float s0 = 0.f, s1 = 0.f, d0 = 0.f, d1 = 0.f;
    for (int h = 0; h < 128; ++h) {
      float ws = W1[h * 128 + kc];
      float wd = W1[(128 + h) * 128 + kc];
      float n0 = nrow[(half * 2) * 128 + h];
      float n1 = nrow[(half * 2 + 1) * 128 + h];
      s0 = fmaf(n0, ws, s0); s1 = fmaf(n1, ws, s1);
      d0 = fmaf(n0, wd, d0); d1 = fmaf(n1, wd, d1);
    }
    const float bv = b1[kc];
    const int b = bi0 >> 8, i0 = bi0 & 255;
    S[(bi0 + half * 2) * 128 + kc] = s0 + bv;
    S[(bi0 + half * 2 + 1) * 128 + kc] = s1 + bv;
    DT[(b * 128 + kc) * 256 + i0 + half * 2] = d0;
    DT[(b * 128 + kc) * 256 + i0 + half * 2 + 1] = d1;
  } else {
    int gid = (blockIdx.x - 256) * 256 + t;
    for (int idx = gid; idx < 16384; idx += 2048)
      W1hT[idx] = f2bf(W1[(256 + (idx & 127)) * 128 + (idx >> 7)]);
    for (int idx = gid; idx < 4096; idx += 2048)
      W1eT[idx] = f2bf(W1[(384 + (idx & 31)) * 128 + (idx >> 5)]);
    for (int idx = gid; idx < 16384; idx += 2048)
      W2T[idx] = f2bf(W2[(idx & 127) * 128 + (idx >> 7)]);
  }
}

// ---------------- fused main kernel ----------------
#define LDH 136  // sH row stride in ushorts (272B)

__launch_bounds__(256, 3)
__global__ void fused_kernel(const float* __restrict__ dart, const float* __restrict__ edge,
                             const float* __restrict__ S, const float* __restrict__ DT,
                             const unsigned short* __restrict__ W1hT,
                             const unsigned short* __restrict__ W1eT,
                             const unsigned short* __restrict__ W2T,
                             const float* __restrict__ b2, float* __restrict__ out) {
  __shared__ unsigned short sH[2][64 * LDH];   // 34816 B total

  const int tid = threadIdx.x;
  const int lane = tid & 63;
  const int w = tid >> 6;      // wave 0..3 (owns kc/n slice w*32..w*32+32)
  const int g = lane >> 4;     // 16-lane group 0..3
  const int lj = lane & 15;

  const int bi = blockIdx.x;   // b*256 + i
  const int b = bi >> 8;
  const size_t m_base = (size_t)bi * 256;

  // --- resident per-block constants ---
  bf16x8 wh[2][4], we[2];
#pragma unroll
  for (int kt = 0; kt < 2; ++kt)
#pragma unroll
    for (int hs = 0; hs < 4; ++hs)
      wh[kt][hs] = *reinterpret_cast<const bf16x8*>(&W1hT[(w * 32 + kt * 16 + lj) * 128 + hs * 32 + g * 8]);
#pragma unroll
  for (int kt = 0; kt < 2; ++kt)
    we[kt] = *reinterpret_cast<const bf16x8*>(&W1eT[(w * 32 + kt * 16 + lj) * 32 + g * 8]);

  float sv[2][4], b2v[2][4];
#pragma unroll
  for (int kt = 0; kt < 2; ++kt)
#pragma unroll
    for (int r = 0; r < 4; ++r)
      sv[kt][r] = S[bi * 128 + w * 32 + kt * 16 + g * 4 + r];
#pragma unroll
  for (int nt = 0; nt < 2; ++nt)
#pragma unroll
    for (int r = 0; r < 4; ++r)
      b2v[nt][r] = b2[w * 32 + nt * 16 + g * 4 + r];

  for (int t = 0; t < 4; ++t) {
    const int j0 = t * 64;
    // per-lane fragment bases: B-frag for (jt,hs) = dart[j0+jt*16+lj][hs*32+g*8 .. +8]
    const float* dbase = dart + (m_base + j0 + lj) * 128 + g * 8;
    const float* ebase = edge + (m_base + j0 + lj) * 32 + g * 8;

    f32x4 acc1[2][4];
#pragma unroll
    for (int kt = 0; kt < 2; ++kt)
#pragma unroll
      for (int jt = 0; jt < 4; ++jt) acc1[kt][jt] = (f32x4){0.f, 0.f, 0.f, 0.f};

    // --- GEMM1: 16 dart steps + 4 edge steps, 1-deep load pipeline, global->reg ---
    float4 c0, c1, n0, n1;
    c0 = reinterpret_cast<const float4*>(dbase)[0];
    c1 = reinterpret_cast<const float4*>(dbase)[1];
#pragma unroll
    for (int s = 0; s < 16; ++s) {
      {
        const float* p = (s < 15) ? (dbase + ((s + 1) & 3) * 2048 + ((s + 1) >> 2) * 32)
                                  : ebase;   // hand off to edge step 0
        n0 = reinterpret_cast<const float4*>(p)[0];
        n1 = reinterpret_cast<const float4*>(p)[1];
      }
      bf16x8 bd = cvt8(c0, c1);
      acc1[0][s & 3] = __builtin_amdgcn_mfma_f32_16x16x32_bf16(wh[0][s >> 2], bd, acc1[0][s & 3], 0, 0, 0);
      acc1[1][s & 3] = __builtin_amdgcn_mfma_f32_16x16x32_bf16(wh[1][s >> 2], bd, acc1[1][s & 3], 0, 0, 0);
      c0 = n0; c1 = n1;
    }

    // --- DT loads (L2-resident); latency covered by edge MFMAs + pack + TLP ---
    float dv[2][4][4];
    {
      const float* DTp = DT + (size_t)(b * 128 + w * 32) * 256 + j0;
#pragma unroll
      for (int kt = 0; kt < 2; ++kt)
#pragma unroll
        for (int jt = 0; jt < 4; ++jt)
#pragma unroll
          for (int r = 0; r < 4; ++r)
            dv[kt][jt][r] = DTp[(kt * 16 + g * 4 + r) * 256 + jt * 16 + lj];
    }

#pragma unroll
    for (int s = 0; s < 4; ++s) {
      if (s < 3) {
        const float* p = ebase + (s + 1) * 512;
        n0 = reinterpret_cast<const float4*>(p)[0];
        n1 = reinterpret_cast<const float4*>(p)[1];
      }
      bf16x8 bd = cvt8(c0, c1);
      acc1[0][s] = __builtin_amdgcn_mfma_f32_16x16x32_bf16(we[0], bd, acc1[0][s], 0, 0, 0);
      acc1[1][s] = __builtin_amdgcn_mfma_f32_16x16x32_bf16(we[1], bd, acc1[1][s], 0, 0, 0);
      c0 = n0; c1 = n1;
    }

    // --- add S + D, relu, pack -> sH[t&1] as [j][kc] bf16 (R3-verified path) ---
    unsigned short* sHc = sH[t & 1];
#pragma unroll
    for (int kt = 0; kt < 2; ++kt) {
#pragma unroll
      for (int jt = 0; jt < 4; ++jt) {
        bf16x4 hp;
#pragma unroll
        for (int r = 0; r < 4; ++r) {
          float x = acc1[kt][jt][r] + sv[kt][r] + dv[kt][jt][r];
          x = x > 0.f ? x : 0.f;
          hp[r] = (short)f2bf(x);
        }
        *reinterpret_cast<bf16x4*>(&sHc[(jt * 16 + lj) * LDH + w * 32 + kt * 16 + g * 4]) = hp;
      }
    }

    // ONE barrier per tile (full drain is cheap: no prefetch in flight here)
    __syncthreads();

    // --- GEMM2 (swapped): W2T fragments reloaded per tile (L1-hot) ---
    bf16x8 w2f[4][2];
#pragma unroll
    for (int ks = 0; ks < 4; ++ks)
#pragma unroll
      for (int nt = 0; nt < 2; ++nt)
        w2f[ks][nt] = *reinterpret_cast<const bf16x8*>(&W2T[(w * 32 + nt * 16 + lj) * 128 + ks * 32 + g * 8]);

    f32x4 acc2[4][2];
#pragma unroll
    for (int jt = 0; jt < 4; ++jt)
#pragma unroll
      for (int nt = 0; nt < 2; ++nt) acc2[jt][nt] = (f32x4){0.f, 0.f, 0.f, 0.f};

#pragma unroll
    for (int ks = 0; ks < 4; ++ks) {
#pragma unroll
      for (int jt = 0; jt < 4; ++jt) {
        bf16x8 ah = *reinterpret_cast<const bf16x8*>(&sHc[(jt * 16 + lj) * LDH + ks * 32 + g * 8]);
        acc2[jt][0] = __builtin_amdgcn_mfma_f32_16x16x32_bf16(w2f[ks][0], ah, acc2[jt][0], 0, 0, 0);
        acc2[jt][1] = __builtin_amdgcn_mfma_f32_16x16x32_bf16(w2f[ks][1], ah, acc2[jt][1], 0, 0, 0);
      }
    }

    // --- stores (dwordx4) ---
    {
      float* op = out + (m_base + j0) * 128 + w * 32;
#pragma unroll
      for (int jt = 0; jt < 4; ++jt)
#pragma unroll
        for (int nt = 0; nt < 2; ++nt) {
          float4 v;
          v.x = acc2[jt][nt][0] + b2v[nt][0];
          v.y = acc2[jt][nt][1] + b2v[nt][1];
          v.z = acc2[jt][nt][2] + b2v[nt][2];
          v.w = acc2[jt][nt][3] + b2v[nt][3];
          *reinterpret_cast<float4*>(&op[(size_t)(jt * 16 + lj) * 128 + nt * 16 + g * 4]) = v;
        }
    }
    // no trailing barrier: pack(t+1) targets sH[(t+1)&1]; its prior readers
    // (GEMM2(t-1)) are fenced by the tile-t __syncthreads in every wave.
  }
}

extern "C" void kernel_launch(void* const* d_in, const int* in_sizes, int n_in,
                              void* d_out, int out_size, void* d_ws, size_t ws_size,
                              hipStream_t stream) {
  const float* node = (const float*)d_in[0];
  const float* dart = (const float*)d_in[1];
  const float* edge = (const float*)d_in[2];
  const float* W1   = (const float*)d_in[3];
  const float* b1   = (const float*)d_in[4];
  const float* W2   = (const float*)d_in[5];
  const float* b2   = (const float*)d_in[6];
  float* out = (float*)d_out;

  float* S  = (float*)d_ws;                       // 131072 f32
  float* DT = S + 131072;                         // 131072 f32
  unsigned short* W1hT = (unsigned short*)(DT + 131072);  // 16384 bf16
  unsigned short* W1eT = W1hT + 16384;            // 4096 bf16
  unsigned short* W2T  = W1eT + 4096;             // 16384 bf16

  hipLaunchKernelGGL(prep_kernel, dim3(264), dim3(256), 0, stream,
                     node, W1, b1, W2, S, DT, W1hT, W1eT, W2T);
  hipLaunchKernelGGL(fused_kernel, dim3(1024), dim3(256), 0, stream,
                     dart, edge, S, DT, W1hT, W1eT, W2T, b2, out);
}

// Round 8
// 145.127 us; speedup vs baseline: 1.5915x; 1.5915x over previous
//
#include <hip/hip_runtime.h>
#include <hip/hip_bf16.h>

// B=4, N=256, H=128, E=32. M = B*N*N = 262144 rows, out[m][128] f32.

typedef __attribute__((ext_vector_type(8))) short bf16x8;
typedef __attribute__((ext_vector_type(4))) short bf16x4;
typedef __attribute__((ext_vector_type(4))) float f32x4;

__device__ __forceinline__ unsigned short f2bf(float f) {
  union { float f; unsigned u; } v; v.f = f;
  unsigned r = v.u + 0x7FFFu + ((v.u >> 16) & 1u);  // RNE
  return (unsigned short)(r >> 16);
}

__device__ __forceinline__ bf16x8 cvt8(float4 a, float4 b) {
  bf16x8 r;
  r[0] = (short)f2bf(a.x); r[1] = (short)f2bf(a.y);
  r[2] = (short)f2bf(a.z); r[3] = (short)f2bf(a.w);
  r[4] = (short)f2bf(b.x); r[5] = (short)f2bf(b.y);
  r[6] = (short)f2bf(b.z); r[7] = (short)f2bf(b.w);
  return r;
}

// ---------------- prep: S = node@W1s + b1 ; D[b][j][k] = node@W1d ; bf16 transposed weights ----
__global__ void prep_kernel(const float* __restrict__ node, const float* __restrict__ W1,
                            const float* __restrict__ b1, const float* __restrict__ W2,
                            float* __restrict__ S, float* __restrict__ D,
                            unsigned short* __restrict__ W1hT, unsigned short* __restrict__ W1eT,
                            unsigned short* __restrict__ W2T) {
  const int t = threadIdx.x;
  if (blockIdx.x < 256) {
    __shared__ float nrow[4 * 128];
    const int bi0 = blockIdx.x * 4;
    if (t < 128)
      reinterpret_cast<float4*>(nrow)[t] = reinterpret_cast<const float4*>(node + bi0 * 128)[t];
    __syncthreads();
    const int kc = t & 127, half = t >> 7;  // rows half*2, half*2+1
    float s0 = 0.f, s1 = 0.f, d0 = 0.f, d1 = 0.f;
    for (int h = 0; h < 128; ++h) {
      float ws = W1[h * 128 + kc];
      float wd = W1[(128 + h) * 128 + kc];
      float n0 = nrow[(half * 2) * 128 + h];
      float n1 = nrow[(half * 2 + 1) * 128 + h];
      s0 = fmaf(n0, ws, s0); s1 = fmaf(n1, ws, s1);
      d0 = fmaf(n0, wd, d0); d1 = fmaf(n1, wd, d1);
    }
    const float bv = b1[kc];
    S[(bi0 + half * 2) * 128 + kc] = s0 + bv;
    S[(bi0 + half * 2 + 1) * 128 + kc] = s1 + bv;
    D[(bi0 + half * 2) * 128 + kc] = d0;      // un-transposed: D[b*256+j][kc]
    D[(bi0 + half * 2 + 1) * 128 + kc] = d1;
  } else {
    int gid = (blockIdx.x - 256) * 256 + t;
    for (int idx = gid; idx < 16384; idx += 2048)
      W1hT[idx] = f2bf(W1[(256 + (idx & 127)) * 128 + (idx >> 7)]);
    for (int idx = gid; idx < 4096; idx += 2048)
      W1eT[idx] = f2bf(W1[(384 + (idx & 31)) * 128 + (idx >> 5)]);
    for (int idx = gid; idx < 16384; idx += 2048)
      W2T[idx] = f2bf(W2[(idx & 127) * 128 + (idx >> 7)]);
  }
}

// ---------------- fused main kernel ----------------
#define LDH 136  // sH row stride in ushorts (272B)

__launch_bounds__(256, 2)
__global__ void fused_kernel(const float* __restrict__ dart, const float* __restrict__ edge,
                             const float* __restrict__ S, const float* __restrict__ D,
                             const unsigned short* __restrict__ W1hT,
                             const unsigned short* __restrict__ W1eT,
                             const unsigned short* __restrict__ W2T,
                             const float* __restrict__ b2, float* __restrict__ out) {
  __shared__ unsigned short sH[2][64 * LDH];   // 34816 B total

  const int tid = threadIdx.x;
  const int lane = tid & 63;
  const int w = tid >> 6;      // wave 0..3 (owns kc/n slice w*32..w*32+32)
  const int g = lane >> 4;     // 16-lane group 0..3
  const int lj = lane & 15;

  // bijective XCD swizzle (1024 % 8 == 0): 128 consecutive bi per XCD share b
  const int bi = (blockIdx.x & 7) * 128 + (blockIdx.x >> 3);
  const int b = bi >> 8;
  const size_t m_base = (size_t)bi * 256;

  // --- resident per-block constants ---
  bf16x8 wh[2][4], we[2];
#pragma unroll
  for (int kt = 0; kt < 2; ++kt)
#pragma unroll
    for (int hs = 0; hs < 4; ++hs)
      wh[kt][hs] = *reinterpret_cast<const bf16x8*>(&W1hT[(w * 32 + kt * 16 + lj) * 128 + hs * 32 + g * 8]);
#pragma unroll
  for (int kt = 0; kt < 2; ++kt)
    we[kt] = *reinterpret_cast<const bf16x8*>(&W1eT[(w * 32 + kt * 16 + lj) * 32 + g * 8]);

  float sv[2][4], b2v[2][4];
#pragma unroll
  for (int kt = 0; kt < 2; ++kt)
#pragma unroll
    for (int r = 0; r < 4; ++r)
      sv[kt][r] = S[bi * 128 + w * 32 + kt * 16 + g * 4 + r];
#pragma unroll
  for (int nt = 0; nt < 2; ++nt)
#pragma unroll
    for (int r = 0; r < 4; ++r)
      b2v[nt][r] = b2[w * 32 + nt * 16 + g * 4 + r];

  for (int t = 0; t < 4; ++t) {
    const int j0 = t * 64;
    // per-lane fragment bases: B-frag for (jt,hs) = dart[j0+jt*16+lj][hs*32+g*8 .. +8]
    const float* dbase = dart + (m_base + j0 + lj) * 128 + g * 8;
    const float* ebase = edge + (m_base + j0 + lj) * 32 + g * 8;

    f32x4 acc1[2][4];
#pragma unroll
    for (int kt = 0; kt < 2; ++kt)
#pragma unroll
      for (int jt = 0; jt < 4; ++jt) acc1[kt][jt] = (f32x4){0.f, 0.f, 0.f, 0.f};

    // --- GEMM1: 16 dart steps, 1-deep load pipeline, global->reg ---
    float4 c0, c1, n0, n1;
    c0 = reinterpret_cast<const float4*>(dbase)[0];
    c1 = reinterpret_cast<const float4*>(dbase)[1];
#pragma unroll
    for (int s = 0; s < 16; ++s) {
      {
        const float* p = (s < 15) ? (dbase + ((s + 1) & 3) * 2048 + ((s + 1) >> 2) * 32)
                                  : ebase;   // hand off to edge step 0
        n0 = reinterpret_cast<const float4*>(p)[0];
        n1 = reinterpret_cast<const float4*>(p)[1];
      }
      bf16x8 bd = cvt8(c0, c1);
      acc1[0][s & 3] = __builtin_amdgcn_mfma_f32_16x16x32_bf16(wh[0][s >> 2], bd, acc1[0][s & 3], 0, 0, 0);
      acc1[1][s & 3] = __builtin_amdgcn_mfma_f32_16x16x32_bf16(wh[1][s >> 2], bd, acc1[1][s & 3], 0, 0, 0);
      c0 = n0; c1 = n1;
    }

    // --- D-term loads: 8x float4 from D[b][j][kc] (L2-hot via XCD swizzle) ---
    f32x4 dv4[2][4];
    {
      const float* Dp = D + (size_t)(b * 256 + j0 + lj) * 128 + w * 32 + g * 4;
#pragma unroll
      for (int kt = 0; kt < 2; ++kt)
#pragma unroll
        for (int jt = 0; jt < 4; ++jt)
          dv4[kt][jt] = *reinterpret_cast<const f32x4*>(&Dp[(size_t)(jt * 16) * 128 + kt * 16]);
    }

    // --- 4 edge steps (K=32 over E) ---
#pragma unroll
    for (int s = 0; s < 4; ++s) {
      if (s < 3) {
        const float* p = ebase + (s + 1) * 512;
        n0 = reinterpret_cast<const float4*>(p)[0];
        n1 = reinterpret_cast<const float4*>(p)[1];
      }
      bf16x8 bd = cvt8(c0, c1);
      acc1[0][s] = __builtin_amdgcn_mfma_f32_16x16x32_bf16(we[0], bd, acc1[0][s], 0, 0, 0);
      acc1[1][s] = __builtin_amdgcn_mfma_f32_16x16x32_bf16(we[1], bd, acc1[1][s], 0, 0, 0);
      c0 = n0; c1 = n1;
    }

    // --- add S + D, relu, pack -> sH[t&1] as [j][kc] bf16 ---
    unsigned short* sHc = sH[t & 1];
#pragma unroll
    for (int kt = 0; kt < 2; ++kt) {
#pragma unroll
      for (int jt = 0; jt < 4; ++jt) {
        bf16x4 hp;
#pragma unroll
        for (int r = 0; r < 4; ++r) {
          float x = acc1[kt][jt][r] + sv[kt][r] + dv4[kt][jt][r];
          x = x > 0.f ? x : 0.f;
          hp[r] = (short)f2bf(x);
        }
        *reinterpret_cast<bf16x4*>(&sHc[(jt * 16 + lj) * LDH + w * 32 + kt * 16 + g * 4]) = hp;
      }
    }

    // ONE barrier per tile (full drain is cheap: no cross-tile prefetch in flight)
    __syncthreads();

    // --- GEMM2 (swapped): W2T fragments reloaded per tile (L1-hot) ---
    bf16x8 w2f[4][2];
#pragma unroll
    for (int ks = 0; ks < 4; ++ks)
#pragma unroll
      for (int nt = 0; nt < 2; ++nt)
        w2f[ks][nt] = *reinterpret_cast<const bf16x8*>(&W2T[(w * 32 + nt * 16 + lj) * 128 + ks * 32 + g * 8]);

    f32x4 acc2[4][2];
#pragma unroll
    for (int jt = 0; jt < 4; ++jt)
#pragma unroll
      for (int nt = 0; nt < 2; ++nt) acc2[jt][nt] = (f32x4){0.f, 0.f, 0.f, 0.f};

#pragma unroll
    for (int ks = 0; ks < 4; ++ks) {
#pragma unroll
      for (int jt = 0; jt < 4; ++jt) {
        bf16x8 ah = *reinterpret_cast<const bf16x8*>(&sHc[(jt * 16 + lj) * LDH + ks * 32 + g * 8]);
        acc2[jt][0] = __builtin_amdgcn_mfma_f32_16x16x32_bf16(w2f[ks][0], ah, acc2[jt][0], 0, 0, 0);
        acc2[jt][1] = __builtin_amdgcn_mfma_f32_16x16x32_bf16(w2f[ks][1], ah, acc2[jt][1], 0, 0, 0);
      }
    }

    // --- stores (dwordx4) ---
    {
      float* op = out + (m_base + j0) * 128 + w * 32;
#pragma unroll
      for (int jt = 0; jt < 4; ++jt)
#pragma unroll
        for (int nt = 0; nt < 2; ++nt) {
          float4 v;
          v.x = acc2[jt][nt][0] + b2v[nt][0];
          v.y = acc2[jt][nt][1] + b2v[nt][1];
          v.z = acc2[jt][nt][2] + b2v[nt][2];
          v.w = acc2[jt][nt][3] + b2v[nt][3];
          *reinterpret_cast<float4*>(&op[(size_t)(jt * 16 + lj) * 128 + nt * 16 + g * 4]) = v;
        }
    }
    // no trailing barrier: pack(t+1) targets sH[(t+1)&1]; its prior readers
    // (GEMM2(t-1)) are fenced by the tile-t __syncthreads in every wave.
  }
}

extern "C" void kernel_launch(void* const* d_in, const int* in_sizes, int n_in,
                              void* d_out, int out_size, void* d_ws, size_t ws_size,
                              hipStream_t stream) {
  const float* node = (const float*)d_in[0];
  const float* dart = (const float*)d_in[1];
  const float* edge = (const float*)d_in[2];
  const float* W1   = (const float*)d_in[3];
  const float* b1   = (const float*)d_in[4];
  const float* W2   = (const float*)d_in[5];
  const float* b2   = (const float*)d_in[6];
  float* out = (float*)d_out;

  float* S  = (float*)d_ws;                       // 131072 f32
  float* D  = S + 131072;                         // 131072 f32
  unsigned short* W1hT = (unsigned short*)(D + 131072);   // 16384 bf16
  unsigned short* W1eT = W1hT + 16384;            // 4096 bf16
  unsigned short* W2T  = W1eT + 4096;             // 16384 bf16

  hipLaunchKernelGGL(prep_kernel, dim3(264), dim3(256), 0, stream,
                     node, W1, b1, W2, S, D, W1hT, W1eT, W2T);
  hipLaunchKernelGGL(fused_kernel, dim3(1024), dim3(256), 0, stream,
                     dart, edge, S, D, W1hT, W1eT, W2T, b2, out);
}

// Round 9
// 98.625 us; speedup vs baseline: 2.3419x; 1.4715x over previous
//
#include <hip/hip_runtime.h>
#include <hip/hip_bf16.h>

// B=4, N=256, H=128, E=32. M = B*N*N = 262144 rows, out[m][128] f32.

typedef __attribute__((ext_vector_type(8))) short bf16x8;
typedef __attribute__((ext_vector_type(4))) short bf16x4;
typedef __attribute__((ext_vector_type(4))) float f32x4;

__device__ __forceinline__ unsigned short f2bf(float f) {
  union { float f; unsigned u; } v; v.f = f;
  unsigned r = v.u + 0x7FFFu + ((v.u >> 16) & 1u);  // RNE
  return (unsigned short)(r >> 16);
}

__device__ __forceinline__ bf16x4 cvt4(float4 a) {
  bf16x4 r;
  r[0] = (short)f2bf(a.x); r[1] = (short)f2bf(a.y);
  r[2] = (short)f2bf(a.z); r[3] = (short)f2bf(a.w);
  return r;
}

// ---------------- prep: S = node@W1s + b1 ; D[b][j][k] = node@W1d ; bf16 transposed weights ----
__global__ void prep_kernel(const float* __restrict__ node, const float* __restrict__ W1,
                            const float* __restrict__ b1, const float* __restrict__ W2,
                            float* __restrict__ S, float* __restrict__ D,
                            unsigned short* __restrict__ W1hT, unsigned short* __restrict__ W1eT,
                            unsigned short* __restrict__ W2T) {
  const int t = threadIdx.x;
  if (blockIdx.x < 256) {
    __shared__ float nrow[4 * 128];
    const int bi0 = blockIdx.x * 4;
    if (t < 128)
      reinterpret_cast<float4*>(nrow)[t] = reinterpret_cast<const float4*>(node + bi0 * 128)[t];
    __syncthreads();
    const int kc = t & 127, half = t >> 7;  // rows half*2, half*2+1
    float s0 = 0.f, s1 = 0.f, d0 = 0.f, d1 = 0.f;
    for (int h = 0; h < 128; ++h) {
      float ws = W1[h * 128 + kc];
      float wd = W1[(128 + h) * 128 + kc];
      float n0 = nrow[(half * 2) * 128 + h];
      float n1 = nrow[(half * 2 + 1) * 128 + h];
      s0 = fmaf(n0, ws, s0); s1 = fmaf(n1, ws, s1);
      d0 = fmaf(n0, wd, d0); d1 = fmaf(n1, wd, d1);
    }
    const float bv = b1[kc];
    S[(bi0 + half * 2) * 128 + kc] = s0 + bv;
    S[(bi0 + half * 2 + 1) * 128 + kc] = s1 + bv;
    D[(bi0 + half * 2) * 128 + kc] = d0;      // D[b*256+j][kc]
    D[(bi0 + half * 2 + 1) * 128 + kc] = d1;
  } else {
    int gid = (blockIdx.x - 256) * 256 + t;
    for (int idx = gid; idx < 16384; idx += 2048)
      W1hT[idx] = f2bf(W1[(256 + (idx & 127)) * 128 + (idx >> 7)]);
    for (int idx = gid; idx < 4096; idx += 2048)
      W1eT[idx] = f2bf(W1[(384 + (idx & 31)) * 128 + (idx >> 5)]);
    for (int idx = gid; idx < 16384; idx += 2048)
      W2T[idx] = f2bf(W2[(idx & 127) * 128 + (idx >> 7)]);
  }
}

// ---------------- fused main kernel ----------------
#define LDH 140  // dart/h LDS row stride in ushorts (280B = 70 dw, 70%32=6 -> 2-way max)
#define LDE 36   // edge LDS row stride (72B)

__launch_bounds__(512, 4)
__global__ void fused_kernel(const float* __restrict__ dart, const float* __restrict__ edge,
                             const float* __restrict__ S, const float* __restrict__ D,
                             const unsigned short* __restrict__ W1hT,
                             const unsigned short* __restrict__ W1eT,
                             const unsigned short* __restrict__ W2T,
                             const float* __restrict__ b2, float* __restrict__ out) {
  __shared__ unsigned short sDart[64 * LDH];     // 17920 B
  __shared__ unsigned short sEdge[64 * LDE];     //  4608 B
  __shared__ unsigned short sH[2][64 * LDH];     // 35840 B  (total 58368)

  const int tid = threadIdx.x;
  const int lane = tid & 63;
  const int wv = tid >> 6;     // wave 0..7
  const int g = lane >> 4;     // 16-lane group 0..3
  const int lj = lane & 15;

  // bijective XCD swizzle (1024 % 8 == 0)
  const int bi = (blockIdx.x & 7) * 128 + (blockIdx.x >> 3);
  const int b = bi >> 8;
  const size_t m_base = (size_t)bi * 256;

  // --- GEMM1 constants: wave owns kc-slice [wv*16, wv*16+16) ---
  bf16x8 wh[4], we;
#pragma unroll
  for (int hs = 0; hs < 4; ++hs)
    wh[hs] = *reinterpret_cast<const bf16x8*>(&W1hT[(wv * 16 + lj) * 128 + hs * 32 + g * 8]);
  we = *reinterpret_cast<const bf16x8*>(&W1eT[(wv * 16 + lj) * 32 + g * 8]);

  float sv[4];
#pragma unroll
  for (int r = 0; r < 4; ++r)
    sv[r] = S[bi * 128 + wv * 16 + g * 4 + r];

  // --- GEMM2 split: jh = j-half (0..1), wn = n-slice of 32 (0..3) ---
  const int jh = wv >> 2;
  const int wn = wv & 3;
  float b2v[2][4];
#pragma unroll
  for (int nt = 0; nt < 2; ++nt)
#pragma unroll
    for (int r = 0; r < 4; ++r)
      b2v[nt][r] = b2[wn * 32 + nt * 16 + g * 4 + r];

  const int srow = tid >> 3;           // staging row 0..63
  const int scol = (tid & 3 ? (tid & 7) * 4 : (tid & 7) * 4);  // (tid&7)*4 floats

  for (int t = 0; t < 4; ++t) {
    const int j0 = t * 64;

    // --- stage dart & edge tile -> LDS (f32 -> bf16), 128B-contiguous per 8 lanes ---
    {
      const float* dsrc = dart + (m_base + j0 + srow) * 128 + scol;
      float4 rd0 = *reinterpret_cast<const float4*>(dsrc);
      float4 rd1 = *reinterpret_cast<const float4*>(dsrc + 32);
      float4 rd2 = *reinterpret_cast<const float4*>(dsrc + 64);
      float4 rd3 = *reinterpret_cast<const float4*>(dsrc + 96);
      float4 re  = *reinterpret_cast<const float4*>(edge + (m_base + j0 + srow) * 32 + scol);
      *reinterpret_cast<bf16x4*>(&sDart[srow * LDH + scol])      = cvt4(rd0);
      *reinterpret_cast<bf16x4*>(&sDart[srow * LDH + scol + 32]) = cvt4(rd1);
      *reinterpret_cast<bf16x4*>(&sDart[srow * LDH + scol + 64]) = cvt4(rd2);
      *reinterpret_cast<bf16x4*>(&sDart[srow * LDH + scol + 96]) = cvt4(rd3);
      *reinterpret_cast<bf16x4*>(&sEdge[srow * LDE + scol])      = cvt4(re);
    }
    __syncthreads();   // B1: staging visible

    // --- D-term loads issued first (latency hides under GEMM1 MFMAs) ---
    f32x4 dv4[4];
    {
      const float* Dp = D + (size_t)(b * 256 + j0 + lj) * 128 + wv * 16 + g * 4;
#pragma unroll
      for (int jt = 0; jt < 4; ++jt)
        dv4[jt] = *reinterpret_cast<const f32x4*>(&Dp[(size_t)(jt * 16) * 128]);
    }

    // --- GEMM1: pre^T[kc][j], wave owns kc-slice [wv*16, +16) ---
    f32x4 acc1[4];
#pragma unroll
    for (int jt = 0; jt < 4; ++jt) acc1[jt] = (f32x4){0.f, 0.f, 0.f, 0.f};

#pragma unroll
    for (int hs = 0; hs < 4; ++hs) {
#pragma unroll
      for (int jt = 0; jt < 4; ++jt) {
        bf16x8 bd = *reinterpret_cast<const bf16x8*>(&sDart[(jt * 16 + lj) * LDH + hs * 32 + g * 8]);
        acc1[jt] = __builtin_amdgcn_mfma_f32_16x16x32_bf16(wh[hs], bd, acc1[jt], 0, 0, 0);
      }
    }
#pragma unroll
    for (int jt = 0; jt < 4; ++jt) {
      bf16x8 be = *reinterpret_cast<const bf16x8*>(&sEdge[(jt * 16 + lj) * LDE + g * 8]);
      acc1[jt] = __builtin_amdgcn_mfma_f32_16x16x32_bf16(we, be, acc1[jt], 0, 0, 0);
    }

    // --- add S + D, relu, pack -> sH[t&1] as [j][kc] bf16 ---
    unsigned short* sHc = sH[t & 1];
#pragma unroll
    for (int jt = 0; jt < 4; ++jt) {
      bf16x4 hp;
#pragma unroll
      for (int r = 0; r < 4; ++r) {
        float x = acc1[jt][r] + sv[r] + dv4[jt][r];
        x = x > 0.f ? x : 0.f;
        hp[r] = (short)f2bf(x);
      }
      *reinterpret_cast<bf16x4*>(&sHc[(jt * 16 + lj) * LDH + wv * 16 + g * 4]) = hp;
    }
    __syncthreads();   // B2: sH visible; all GEMM1 reads done (next staging safe)

    // --- GEMM2: wave owns 32j x 32n sub-tile; w2f reloaded per tile (L1-hot) ---
    bf16x8 w2f[4][2];
#pragma unroll
    for (int ks = 0; ks < 4; ++ks)
#pragma unroll
      for (int nt = 0; nt < 2; ++nt)
        w2f[ks][nt] = *reinterpret_cast<const bf16x8*>(&W2T[(wn * 32 + nt * 16 + lj) * 128 + ks * 32 + g * 8]);

    f32x4 acc2[2][2];
#pragma unroll
    for (int jt = 0; jt < 2; ++jt)
#pragma unroll
      for (int nt = 0; nt < 2; ++nt) acc2[jt][nt] = (f32x4){0.f, 0.f, 0.f, 0.f};

#pragma unroll
    for (int ks = 0; ks < 4; ++ks) {
#pragma unroll
      for (int jt = 0; jt < 2; ++jt) {
        bf16x8 ah = *reinterpret_cast<const bf16x8*>(&sHc[(jh * 32 + jt * 16 + lj) * LDH + ks * 32 + g * 8]);
        acc2[jt][0] = __builtin_amdgcn_mfma_f32_16x16x32_bf16(w2f[ks][0], ah, acc2[jt][0], 0, 0, 0);
        acc2[jt][1] = __builtin_amdgcn_mfma_f32_16x16x32_bf16(w2f[ks][1], ah, acc2[jt][1], 0, 0, 0);
      }
    }

    // --- stores: full 128B line per wave-row ---
    {
      float* op = out + (m_base + j0) * 128;
#pragma unroll
      for (int jt = 0; jt < 2; ++jt)
#pragma unroll
        for (int nt = 0; nt < 2; ++nt) {
          float4 v;
          v.x = acc2[jt][nt][0] + b2v[nt][0];
          v.y = acc2[jt][nt][1] + b2v[nt][1];
          v.z = acc2[jt][nt][2] + b2v[nt][2];
          v.w = acc2[jt][nt][3] + b2v[nt][3];
          *reinterpret_cast<float4*>(&op[(size_t)(jh * 32 + jt * 16 + lj) * 128 + wn * 32 + nt * 16 + g * 4]) = v;
        }
    }
    // no third barrier: staging(t+1) is fenced by B2(t) for sDart (GEMM1 reads done);
    // GEMM2(t) reads sH[t&1] run concurrently with staging(t+1) (different regions);
    // pack(t+1) comes after B1(t+1), i.e., after every wave's GEMM2(t) reads.
  }
}

extern "C" void kernel_launch(void* const* d_in, const int* in_sizes, int n_in,
                              void* d_out, int out_size, void* d_ws, size_t ws_size,
                              hipStream_t stream) {
  const float* node = (const float*)d_in[0];
  const float* dart = (const float*)d_in[1];
  const float* edge = (const float*)d_in[2];
  const float* W1   = (const float*)d_in[3];
  const float* b1   = (const float*)d_in[4];
  const float* W2   = (const float*)d_in[5];
  const float* b2   = (const float*)d_in[6];
  float* out = (float*)d_out;

  float* S  = (float*)d_ws;                       // 131072 f32
  float* D  = S + 131072;                         // 131072 f32
  unsigned short* W1hT = (unsigned short*)(D + 131072);   // 16384 bf16
  unsigned short* W1eT = W1hT + 16384;            // 4096 bf16
  unsigned short* W2T  = W1eT + 4096;             // 16384 bf16

  hipLaunchKernelGGL(prep_kernel, dim3(264), dim3(256), 0, stream,
                     node, W1, b1, W2, S, D, W1hT, W1eT, W2T);
  hipLaunchKernelGGL(fused_kernel, dim3(1024), dim3(512), 0, stream,
                     dart, edge, S, D, W1hT, W1eT, W2T, b2, out);
}

// Round 10
// 96.181 us; speedup vs baseline: 2.4014x; 1.0254x over previous
//
#include <hip/hip_runtime.h>
#include <hip/hip_bf16.h>

// B=4, N=256, H=128, E=32. M = B*N*N = 262144 rows, out[m][128] f32.

typedef __attribute__((ext_vector_type(8))) short bf16x8;
typedef __attribute__((ext_vector_type(4))) short bf16x4;
typedef __attribute__((ext_vector_type(4))) float f32x4;

__device__ __forceinline__ unsigned short f2bf(float f) {
  union { float f; unsigned u; } v; v.f = f;
  unsigned r = v.u + 0x7FFFu + ((v.u >> 16) & 1u);  // RNE
  return (unsigned short)(r >> 16);
}

__device__ __forceinline__ bf16x8 cvt8(float4 a, float4 b) {
  bf16x8 r;
  r[0] = (short)f2bf(a.x); r[1] = (short)f2bf(a.y);
  r[2] = (short)f2bf(a.z); r[3] = (short)f2bf(a.w);
  r[4] = (short)f2bf(b.x); r[5] = (short)f2bf(b.y);
  r[6] = (short)f2bf(b.z); r[7] = (short)f2bf(b.w);
  return r;
}
__device__ __forceinline__ bf16x4 cvt4(float4 a) {
  bf16x4 r;
  r[0] = (short)f2bf(a.x); r[1] = (short)f2bf(a.y);
  r[2] = (short)f2bf(a.z); r[3] = (short)f2bf(a.w);
  return r;
}
__device__ __forceinline__ float bf2f(short u) {
  union { float f; unsigned v; } x;
  x.v = ((unsigned)(unsigned short)u) << 16;
  return x.f;
}

// T2 XOR swizzle for 256B-row LDS tiles (write and read must match)
__device__ __forceinline__ unsigned short* swz(unsigned short* base, int row, int inrowbyte) {
  return (unsigned short*)((char*)base + row * 256 + (inrowbyte ^ ((row & 7) << 4)));
}

// ---------------- prep: S = node@W1s + b1 ; Dbf[b*256+j][k] = bf16(node@W1d) ; bf16 transposed weights ----
__global__ void prep_kernel(const float* __restrict__ node, const float* __restrict__ W1,
                            const float* __restrict__ b1, const float* __restrict__ W2,
                            float* __restrict__ S, unsigned short* __restrict__ Dbf,
                            unsigned short* __restrict__ W1hT, unsigned short* __restrict__ W1eT,
                            unsigned short* __restrict__ W2T) {
  const int t = threadIdx.x;
  if (blockIdx.x < 256) {
    __shared__ float nrow[4 * 128];
    const int bi0 = blockIdx.x * 4;
    if (t < 128)
      reinterpret_cast<float4*>(nrow)[t] = reinterpret_cast<const float4*>(node + bi0 * 128)[t];
    __syncthreads();
    const int kc = t & 127, half = t >> 7;  // rows half*2, half*2+1
    float s0 = 0.f, s1 = 0.f, d0 = 0.f, d1 = 0.f;
    for (int h = 0; h < 128; ++h) {
      float ws = W1[h * 128 + kc];
      float wd = W1[(128 + h) * 128 + kc];
      float n0 = nrow[(half * 2) * 128 + h];
      float n1 = nrow[(half * 2 + 1) * 128 + h];
      s0 = fmaf(n0, ws, s0); s1 = fmaf(n1, ws, s1);
      d0 = fmaf(n0, wd, d0); d1 = fmaf(n1, wd, d1);
    }
    const float bv = b1[kc];
    S[(bi0 + half * 2) * 128 + kc] = s0 + bv;
    S[(bi0 + half * 2 + 1) * 128 + kc] = s1 + bv;
    Dbf[(size_t)(bi0 + half * 2) * 128 + kc] = f2bf(d0);
    Dbf[(size_t)(bi0 + half * 2 + 1) * 128 + kc] = f2bf(d1);
  } else {
    int gid = (blockIdx.x - 256) * 256 + t;
    for (int idx = gid; idx < 16384; idx += 2048)
      W1hT[idx] = f2bf(W1[(256 + (idx & 127)) * 128 + (idx >> 7)]);
    for (int idx = gid; idx < 4096; idx += 2048)
      W1eT[idx] = f2bf(W1[(384 + (idx & 31)) * 128 + (idx >> 5)]);
    for (int idx = gid; idx < 16384; idx += 2048)
      W2T[idx] = f2bf(W2[(idx & 127) * 128 + (idx >> 7)]);
  }
}

// ---------------- fused main kernel: single barrier per tile, full-interval prefetch ----------------
#define LDE 40   // edge LDS row stride in ushorts (80B)

__launch_bounds__(512, 4)
__global__ void fused_kernel(const float* __restrict__ dart, const float* __restrict__ edge,
                             const float* __restrict__ S, const unsigned short* __restrict__ Dbf,
                             const unsigned short* __restrict__ W1hT,
                             const unsigned short* __restrict__ W1eT,
                             const unsigned short* __restrict__ W2T,
                             const float* __restrict__ b2, float* __restrict__ out) {
  __shared__ unsigned short sDart[2][64 * 128];   // 32768 B, swizzled 256B rows
  __shared__ unsigned short sEdge[2][64 * LDE];   // 10240 B
  __shared__ unsigned short sH[2][64 * 128];      // 32768 B, swizzled

  const int tid = threadIdx.x;
  const int lane = tid & 63;
  const int wv = tid >> 6;     // wave 0..7 (GEMM1 kc-slice [wv*16, +16))
  const int g = lane >> 4;     // 16-lane group
  const int lj = lane & 15;

  // bijective XCD swizzle (1024 % 8 == 0)
  const int bi = (blockIdx.x & 7) * 128 + (blockIdx.x >> 3);
  const int b = bi >> 8;
  const size_t m_base = (size_t)bi * 256;

  // --- persistent per-block constants ---
  bf16x8 wh[4], we, w2f[4][2];
#pragma unroll
  for (int hs = 0; hs < 4; ++hs)
    wh[hs] = *reinterpret_cast<const bf16x8*>(&W1hT[(wv * 16 + lj) * 128 + hs * 32 + g * 8]);
  we = *reinterpret_cast<const bf16x8*>(&W1eT[(wv * 16 + lj) * 32 + g * 8]);

  const int jh = wv >> 2;      // GEMM2 j-half
  const int wn = wv & 3;       // GEMM2 n-slice of 32
#pragma unroll
  for (int ks = 0; ks < 4; ++ks)
#pragma unroll
    for (int nt = 0; nt < 2; ++nt)
      w2f[ks][nt] = *reinterpret_cast<const bf16x8*>(&W2T[(wn * 32 + nt * 16 + lj) * 128 + ks * 32 + g * 8]);

  float sv[4], b2v[2][4];
#pragma unroll
  for (int r = 0; r < 4; ++r)
    sv[r] = S[bi * 128 + wv * 16 + g * 4 + r];
#pragma unroll
  for (int nt = 0; nt < 2; ++nt)
#pragma unroll
    for (int r = 0; r < 4; ++r)
      b2v[nt][r] = b2[wn * 32 + nt * 16 + g * 4 + r];

  const int srow = tid >> 3;        // staging row 0..63
  const int sc = tid & 7;           // staging 8-f32 col group

  // ---------- prologue: load + stage tile 0 into buffer 0 ----------
  {
    const float4* p0 = reinterpret_cast<const float4*>(dart + (m_base + srow) * 128 + sc * 8);
    const float4* p1 = reinterpret_cast<const float4*>(dart + (m_base + srow) * 128 + 64 + sc * 8);
    float4 a0 = p0[0], a1 = p0[1], c0 = p1[0], c1 = p1[1];
    float4 e = *reinterpret_cast<const float4*>(edge + (m_base + srow) * 32 + sc * 4);
    *reinterpret_cast<bf16x8*>(swz(sDart[0], srow, sc * 16)) = cvt8(a0, a1);
    *reinterpret_cast<bf16x8*>(swz(sDart[0], srow, 128 + sc * 16)) = cvt8(c0, c1);
    *reinterpret_cast<bf16x4*>(&sEdge[0][srow * LDE + sc * 4]) = cvt4(e);
  }

  for (int t = 0; t <= 4; ++t) {
    __syncthreads();   // the ONLY barrier per iteration

    // --- issue next tile's HBM loads (consumed at iteration END -> full-interval overlap) ---
    float4 ra0, ra1, rc0, rc1, re;
    if (t < 3) {
      const size_t rbase = m_base + (size_t)(t + 1) * 64 + srow;
      const float4* p0 = reinterpret_cast<const float4*>(dart + rbase * 128 + sc * 8);
      const float4* p1 = reinterpret_cast<const float4*>(dart + rbase * 128 + 64 + sc * 8);
      ra0 = p0[0]; ra1 = p0[1]; rc0 = p1[0]; rc1 = p1[1];
      re = *reinterpret_cast<const float4*>(edge + rbase * 32 + sc * 4);
    }

    // --- D-term bf16 loads for tile t (L2-hot; consumed in pack mid-iteration) ---
    bf16x4 dvb[4];
    if (t < 4) {
      const unsigned short* Dp = Dbf + (size_t)(b * 256 + t * 64 + lj) * 128 + wv * 16 + g * 4;
#pragma unroll
      for (int jt = 0; jt < 4; ++jt)
        dvb[jt] = *reinterpret_cast<const bf16x4*>(&Dp[(size_t)(jt * 16) * 128]);
    }

    if (t < 4) {
      // --- GEMM1: pre^T[kc][j] over sDart[t&1] (swizzled reads) ---
      unsigned short* sDc = sDart[t & 1];
      unsigned short* sEc = sEdge[t & 1];
      f32x4 acc1[4];
#pragma unroll
      for (int jt = 0; jt < 4; ++jt) acc1[jt] = (f32x4){0.f, 0.f, 0.f, 0.f};
#pragma unroll
      for (int hs = 0; hs < 4; ++hs) {
#pragma unroll
        for (int jt = 0; jt < 4; ++jt) {
          bf16x8 bd = *reinterpret_cast<const bf16x8*>(swz(sDc, jt * 16 + lj, hs * 64 + g * 16));
          acc1[jt] = __builtin_amdgcn_mfma_f32_16x16x32_bf16(wh[hs], bd, acc1[jt], 0, 0, 0);
        }
      }
#pragma unroll
      for (int jt = 0; jt < 4; ++jt) {
        bf16x8 be = *reinterpret_cast<const bf16x8*>(&sEc[(jt * 16 + lj) * LDE + g * 8]);
        acc1[jt] = __builtin_amdgcn_mfma_f32_16x16x32_bf16(we, be, acc1[jt], 0, 0, 0);
      }

      // --- add S + D, relu, pack -> sH[t&1] (swizzled write) ---
      unsigned short* sHc = sH[t & 1];
#pragma unroll
      for (int jt = 0; jt < 4; ++jt) {
        bf16x4 hp;
#pragma unroll
        for (int r = 0; r < 4; ++r) {
          float x = acc1[jt][r] + sv[r] + bf2f(dvb[jt][r]);
          x = x > 0.f ? x : 0.f;
          hp[r] = (short)f2bf(x);
        }
        *reinterpret_cast<bf16x4*>(swz(sHc, jt * 16 + lj, wv * 32 + g * 8)) = hp;
      }
    }

    if (t > 0) {
      // --- GEMM2 of tile t-1 from sH[(t-1)&1] (visible since BAR) ---
      unsigned short* sHp = sH[(t - 1) & 1];
      f32x4 acc2[2][2];
#pragma unroll
      for (int jt = 0; jt < 2; ++jt)
#pragma unroll
        for (int nt = 0; nt < 2; ++nt) acc2[jt][nt] = (f32x4){0.f, 0.f, 0.f, 0.f};
#pragma unroll
      for (int ks = 0; ks < 4; ++ks) {
#pragma unroll
        for (int jt = 0; jt < 2; ++jt) {
          bf16x8 ah = *reinterpret_cast<const bf16x8*>(swz(sHp, jh * 32 + jt * 16 + lj, ks * 64 + g * 16));
          acc2[jt][0] = __builtin_amdgcn_mfma_f32_16x16x32_bf16(w2f[ks][0], ah, acc2[jt][0], 0, 0, 0);
          acc2[jt][1] = __builtin_amdgcn_mfma_f32_16x16x32_bf16(w2f[ks][1], ah, acc2[jt][1], 0, 0, 0);
        }
      }
      float* op = out + (m_base + (size_t)(t - 1) * 64) * 128;
#pragma unroll
      for (int jt = 0; jt < 2; ++jt)
#pragma unroll
        for (int nt = 0; nt < 2; ++nt) {
          float4 v;
          v.x = acc2[jt][nt][0] + b2v[nt][0];
          v.y = acc2[jt][nt][1] + b2v[nt][1];
          v.z = acc2[jt][nt][2] + b2v[nt][2];
          v.w = acc2[jt][nt][3] + b2v[nt][3];
          *reinterpret_cast<float4*>(&op[(size_t)(jh * 32 + jt * 16 + lj) * 128 + wn * 32 + nt * 16 + g * 4]) = v;
        }
    }

    // --- convert + stage the prefetched tile t+1 (loads had a full interval to land) ---
    if (t < 3) {
      unsigned short* sDn = sDart[(t + 1) & 1];
      *reinterpret_cast<bf16x8*>(swz(sDn, srow, sc * 16)) = cvt8(ra0, ra1);
      *reinterpret_cast<bf16x8*>(swz(sDn, srow, 128 + sc * 16)) = cvt8(rc0, rc1);
      *reinterpret_cast<bf16x4*>(&sEdge[(t + 1) & 1][srow * LDE + sc * 4]) = cvt4(re);
    }
  }
}

extern "C" void kernel_launch(void* const* d_in, const int* in_sizes, int n_in,
                              void* d_out, int out_size, void* d_ws, size_t ws_size,
                              hipStream_t stream) {
  const float* node = (const float*)d_in[0];
  const float* dart = (const float*)d_in[1];
  const float* edge = (const float*)d_in[2];
  const float* W1   = (const float*)d_in[3];
  const float* b1   = (const float*)d_in[4];
  const float* W2   = (const float*)d_in[5];
  const float* b2   = (const float*)d_in[6];
  float* out = (float*)d_out;

  float* S  = (float*)d_ws;                               // 131072 f32
  unsigned short* Dbf  = (unsigned short*)(S + 131072);   // 131072 bf16
  unsigned short* W1hT = Dbf + 131072;                    // 16384 bf16
  unsigned short* W1eT = W1hT + 16384;                    // 4096 bf16
  unsigned short* W2T  = W1eT + 4096;                     // 16384 bf16

  hipLaunchKernelGGL(prep_kernel, dim3(264), dim3(256), 0, stream,
                     node, W1, b1, W2, S, Dbf, W1hT, W1eT, W2T);
  hipLaunchKernelGGL(fused_kernel, dim3(1024), dim3(512), 0, stream,
                     dart, edge, S, Dbf, W1hT, W1eT, W2T, b2, out);
}